// Round 1
// baseline (365.970 us; speedup 1.0000x reference)
//
#include <hip/hip_runtime.h>
#include <hip/hip_bf16.h>

// Problem constants (B=8, T=2048, d_model=512, head_dim=64)
#define TT 2048
#define NB 8
#define DM 512
#define HD 64
static constexpr float SCALE = 0.04419417382415922f; // 512^-0.5

// ---------------------------------------------------------------- zero ----
__global__ __launch_bounds__(256) void zero_kernel(float* __restrict__ p, int n) {
    int i = (blockIdx.x * 256 + threadIdx.x) * 4;
    if (i < n) *(float4*)(p + i) = make_float4(0.f, 0.f, 0.f, 0.f);
}

// ----------------------------------------------------------------- qkv ----
// out[m][row][h] = sum_c x[row][c] * Wm[h][c]
// block: 64-row tile x 64 output cols (one matrix m per blockIdx.y)
__global__ __launch_bounds__(256) void qkv_kernel(
    const float* __restrict__ x, const float* __restrict__ Wk,
    const float* __restrict__ Wq, const float* __restrict__ Wv,
    float* __restrict__ kf, float* __restrict__ qf, float* __restrict__ vf) {
    __shared__ float xs[64 * 68];
    __shared__ float ws[64 * 68];
    const int i0 = blockIdx.x * 64;            // global row tile (0..16383)
    const int m  = blockIdx.y;                 // 0=k,1=q,2=v (input order Wk,Wq,Wv)
    const float* W    = (m == 0) ? Wk : (m == 1) ? Wq : Wv;
    float*       outp = (m == 0) ? kf : (m == 1) ? qf : vf;
    const int t  = threadIdx.x;
    const int tr = t >> 4, tc = t & 15;
    float acc[4][4] = {};
    for (int kc = 0; kc < DM; kc += 64) {
        __syncthreads();
        for (int e = 0; e < 4; ++e) {
            int f = t + 256 * e;               // 0..1023
            int row = f >> 4, h4 = (f & 15) * 4;
            *(float4*)(xs + row * 68 + h4) =
                *(const float4*)(x + (size_t)(i0 + row) * DM + kc + h4);
            *(float4*)(ws + row * 68 + h4) =
                *(const float4*)(W + (size_t)row * DM + kc + h4);
        }
        __syncthreads();
        for (int h4 = 0; h4 < 64; h4 += 4) {
            float4 qv[4], kv[4];
            for (int r = 0; r < 4; ++r)
                qv[r] = *(const float4*)(xs + (tr * 4 + r) * 68 + h4);
            for (int c = 0; c < 4; ++c)
                kv[c] = *(const float4*)(ws + (tc + 16 * c) * 68 + h4);
            for (int r = 0; r < 4; ++r)
                for (int c = 0; c < 4; ++c)
                    acc[r][c] += qv[r].x * kv[c].x + qv[r].y * kv[c].y +
                                 qv[r].z * kv[c].z + qv[r].w * kv[c].w;
        }
    }
    for (int r = 0; r < 4; ++r)
        for (int c = 0; c < 4; ++c)
            outp[(size_t)(i0 + tr * 4 + r) * HD + tc + 16 * c] = acc[r][c];
}

// -------------------------------------------------------------- scores ----
// attn[b][i][j] = (j<=i) ? exp(scale * q_i . k_j) : 0   (unnormalized E)
// colsum[b][j] += sum_i E[i][j]   (atomic, per-block reduced first)
__global__ __launch_bounds__(256) void scores_kernel(
    const float* __restrict__ qf, const float* __restrict__ kf,
    float* __restrict__ attn, float* __restrict__ colsum) {
    const int tj = blockIdx.x, ti = blockIdx.y, b = blockIdx.z;
    const int i0 = ti * 64, j0 = tj * 64;
    const int t  = threadIdx.x;
    float* abase = attn + (size_t)b * TT * TT;
    if (tj > ti) {  // fully above diagonal: write zeros, no compute
        for (int e = 0; e < 4; ++e) {
            int f = t + 256 * e;
            int row = f >> 4, c4 = (f & 15) * 4;
            *(float4*)(abase + (size_t)(i0 + row) * TT + j0 + c4) =
                make_float4(0.f, 0.f, 0.f, 0.f);
        }
        return;
    }
    __shared__ float qs[64 * 68];
    __shared__ float ks[64 * 68];
    for (int e = 0; e < 4; ++e) {
        int f = t + 256 * e;
        int row = f >> 4, h4 = (f & 15) * 4;
        *(float4*)(qs + row * 68 + h4) =
            *(const float4*)(qf + (size_t)(b * TT + i0 + row) * HD + h4);
        *(float4*)(ks + row * 68 + h4) =
            *(const float4*)(kf + (size_t)(b * TT + j0 + row) * HD + h4);
    }
    __syncthreads();
    const int tr = t >> 4, tc = t & 15;
    float acc[4][4] = {};
    for (int h4 = 0; h4 < 64; h4 += 4) {
        float4 qv[4], kv[4];
        for (int r = 0; r < 4; ++r)
            qv[r] = *(const float4*)(qs + (tr * 4 + r) * 68 + h4);
        for (int c = 0; c < 4; ++c)
            kv[c] = *(const float4*)(ks + (tc + 16 * c) * 68 + h4);
        for (int r = 0; r < 4; ++r)
            for (int c = 0; c < 4; ++c)
                acc[r][c] += qv[r].x * kv[c].x + qv[r].y * kv[c].y +
                             qv[r].z * kv[c].z + qv[r].w * kv[c].w;
    }
    float csum[4] = {0.f, 0.f, 0.f, 0.f};
    for (int r = 0; r < 4; ++r) {
        int gi = i0 + tr * 4 + r;
        for (int c = 0; c < 4; ++c) {
            int gj = j0 + tc + 16 * c;
            float e = (gj <= gi) ? __expf(acc[r][c] * SCALE) : 0.0f;
            abase[(size_t)gi * TT + gj] = e;
            csum[c] += e;
        }
    }
    __syncthreads();                 // done reading qs; reuse as reduction pad
    float* red = qs;                 // [16][64]
    for (int c = 0; c < 4; ++c) red[tr * 64 + tc + 16 * c] = csum[c];
    __syncthreads();
    if (t < 64) {
        float s = 0.f;
        for (int g = 0; g < 16; ++g) s += red[g * 64 + t];
        atomicAdd(&colsum[b * TT + j0 + t], s);
    }
}

// ---------------------------------------------------------------- norm ----
// attn[b][i][j] /= colsum[b][j]   (zeros above diagonal stay zero)
__global__ __launch_bounds__(256) void norm_kernel(
    const float* __restrict__ colsum, float* __restrict__ attn) {
    const int seg = blockIdx.x, i = blockIdx.y, b = blockIdx.z;
    const int j0 = seg * 1024;
    if (j0 > i) return;              // whole segment above diagonal
    const int j = j0 + threadIdx.x * 4;
    float* p = attn + (size_t)b * TT * TT + (size_t)i * TT + j;
    float4 a = *(float4*)p;
    const float4 cs = *(const float4*)(colsum + b * TT + j);
    a.x /= cs.x; a.y /= cs.y; a.z /= cs.z; a.w /= cs.w;
    *(float4*)p = a;
}

// ------------------------------------------------------------------ pv ----
// out[b][i][h] += sum_{j in seg, j<=i} attn[b][i][j] * v[b][j][h]
__global__ __launch_bounds__(256) void pv_kernel(
    const float* __restrict__ attn, const float* __restrict__ vf,
    float* __restrict__ out) {
    const int seg = blockIdx.x, ti = blockIdx.y, b = blockIdx.z;
    const int i0 = ti * 64;
    const int jstart = seg * 512;
    if (jstart > i0 + 63) return;
    const int jend = min(jstart + 512, i0 + 64);   // exclusive; 64-aligned
    __shared__ float as[64 * 68];
    __shared__ float vT[64 * 68];
    const int t = threadIdx.x;
    const int tr = t >> 4, tc = t & 15;
    const float* abase = attn + (size_t)b * TT * TT;
    float acc[4][4] = {};
    for (int jc = jstart; jc < jend; jc += 64) {
        __syncthreads();
        for (int e = 0; e < 4; ++e) {
            int f = t + 256 * e;
            int row = f >> 4, q4 = (f & 15) * 4;
            // attn tile: rows i0..i0+63, cols jc..jc+63 (row-major in LDS)
            *(float4*)(as + row * 68 + q4) =
                *(const float4*)(abase + (size_t)(i0 + row) * TT + jc + q4);
            // v tile transposed: vT[h][j-jc]
            float4 vv = *(const float4*)(vf + (size_t)(b * TT + jc + row) * HD + q4);
            vT[(q4 + 0) * 68 + row] = vv.x;
            vT[(q4 + 1) * 68 + row] = vv.y;
            vT[(q4 + 2) * 68 + row] = vv.z;
            vT[(q4 + 3) * 68 + row] = vv.w;
        }
        __syncthreads();
        for (int j4 = 0; j4 < 64; j4 += 4) {
            float4 av[4], vv[4];
            for (int r = 0; r < 4; ++r)
                av[r] = *(const float4*)(as + (tr * 4 + r) * 68 + j4);
            for (int c = 0; c < 4; ++c)
                vv[c] = *(const float4*)(vT + (tc + 16 * c) * 68 + j4);
            for (int r = 0; r < 4; ++r)
                for (int c = 0; c < 4; ++c)
                    acc[r][c] += av[r].x * vv[c].x + av[r].y * vv[c].y +
                                 av[r].z * vv[c].z + av[r].w * vv[c].w;
        }
    }
    for (int r = 0; r < 4; ++r)
        for (int c = 0; c < 4; ++c)
            atomicAdd(&out[(size_t)(b * TT + i0 + tr * 4 + r) * HD + tc + 16 * c],
                      acc[r][c]);
}

// -------------------------------------------------------------- launch ----
extern "C" void kernel_launch(void* const* d_in, const int* in_sizes, int n_in,
                              void* d_out, int out_size, void* d_ws, size_t ws_size,
                              hipStream_t stream) {
    const float* x  = (const float*)d_in[0];
    const float* Wk = (const float*)d_in[1];
    const float* Wq = (const float*)d_in[2];
    const float* Wv = (const float*)d_in[3];
    // d_in[4] = mask sentinel (causal always on) — unused.

    float* out  = (float*)d_out;                       // [B,T,64]
    float* attn = out + (size_t)NB * TT * HD;          // [B,T,T]

    // workspace: k,q,v fp32 [B*T*64] each + colsum [B*T]  (~12.6 MB)
    float* kf = (float*)d_ws;
    float* qf = kf + (size_t)NB * TT * HD;
    float* vf = qf + (size_t)NB * TT * HD;
    float* colsum = vf + (size_t)NB * TT * HD;

    hipLaunchKernelGGL(zero_kernel, dim3(16),   dim3(256), 0, stream, colsum, NB * TT);
    hipLaunchKernelGGL(zero_kernel, dim3(1024), dim3(256), 0, stream, out, NB * TT * HD);
    hipLaunchKernelGGL(qkv_kernel,  dim3(256, 3),     dim3(256), 0, stream,
                       x, Wk, Wq, Wv, kf, qf, vf);
    hipLaunchKernelGGL(scores_kernel, dim3(32, 32, 8), dim3(256), 0, stream,
                       qf, kf, attn, colsum);
    hipLaunchKernelGGL(norm_kernel, dim3(2, 2048, 8),  dim3(256), 0, stream,
                       colsum, attn);
    hipLaunchKernelGGL(pv_kernel,   dim3(4, 32, 8),    dim3(256), 0, stream,
                       attn, vf, out);
}

// Round 2
// 344.862 us; speedup vs baseline: 1.0612x; 1.0612x over previous
//
#include <hip/hip_runtime.h>
#include <hip/hip_bf16.h>

// Problem constants (B=8, T=2048, d_model=512, head_dim=64)
#define TT 2048
#define NB 8
#define DM 512
#define HD 64
static constexpr float SCALE = 0.04419417382415922f; // 512^-0.5

// ---------------------------------------------------------------- zero ----
__global__ __launch_bounds__(256) void zero_kernel(float* __restrict__ p, int n) {
    int i = (blockIdx.x * 256 + threadIdx.x) * 4;
    if (i < n) *(float4*)(p + i) = make_float4(0.f, 0.f, 0.f, 0.f);
}

// ----------------------------------------------------------------- rcp ----
__global__ __launch_bounds__(256) void rcp_kernel(float* __restrict__ p, int n) {
    int i = (blockIdx.x * 256 + threadIdx.x) * 4;
    if (i < n) {
        float4 a = *(float4*)(p + i);
        a.x = 1.0f / a.x; a.y = 1.0f / a.y; a.z = 1.0f / a.z; a.w = 1.0f / a.w;
        *(float4*)(p + i) = a;
    }
}

// ----------------------------------------------------------------- qkv ----
// out[m][row][h] = sum_c x[row][c] * Wm[h][c]
__global__ __launch_bounds__(256) void qkv_kernel(
    const float* __restrict__ x, const float* __restrict__ Wk,
    const float* __restrict__ Wq, const float* __restrict__ Wv,
    float* __restrict__ kf, float* __restrict__ qf, float* __restrict__ vf) {
    __shared__ float xs[64 * 68];
    __shared__ float ws[64 * 68];
    const int i0 = blockIdx.x * 64;            // global row tile (0..16383)
    const int m  = blockIdx.y;                 // 0=k,1=q,2=v
    const float* W    = (m == 0) ? Wk : (m == 1) ? Wq : Wv;
    float*       outp = (m == 0) ? kf : (m == 1) ? qf : vf;
    const int t  = threadIdx.x;
    const int tr = t >> 4, tc = t & 15;
    float acc[4][4] = {};
    for (int kc = 0; kc < DM; kc += 64) {
        __syncthreads();
        for (int e = 0; e < 4; ++e) {
            int f = t + 256 * e;               // 0..1023
            int row = f >> 4, h4 = (f & 15) * 4;
            *(float4*)(xs + row * 68 + h4) =
                *(const float4*)(x + (size_t)(i0 + row) * DM + kc + h4);
            *(float4*)(ws + row * 68 + h4) =
                *(const float4*)(W + (size_t)row * DM + kc + h4);
        }
        __syncthreads();
        for (int h4 = 0; h4 < 64; h4 += 4) {
            float4 qv[4], kv[4];
            for (int r = 0; r < 4; ++r)
                qv[r] = *(const float4*)(xs + (tr * 4 + r) * 68 + h4);
            for (int c = 0; c < 4; ++c)
                kv[c] = *(const float4*)(ws + (tc + 16 * c) * 68 + h4);
            for (int r = 0; r < 4; ++r)
                for (int c = 0; c < 4; ++c)
                    acc[r][c] += qv[r].x * kv[c].x + qv[r].y * kv[c].y +
                                 qv[r].z * kv[c].z + qv[r].w * kv[c].w;
        }
    }
    for (int r = 0; r < 4; ++r)
        for (int c = 0; c < 4; ++c)
            outp[(size_t)(i0 + tr * 4 + r) * HD + tc + 16 * c] = acc[r][c];
}

// -------------------------------------------------------------- scores ----
// attn[b][i][j] = (j<=i) ? exp(scale * q_i . k_j) : 0   (unnormalized E)
// colsum[b][j] += sum_i E[i][j]
__global__ __launch_bounds__(256) void scores_kernel(
    const float* __restrict__ qf, const float* __restrict__ kf,
    float* __restrict__ attn, float* __restrict__ colsum) {
    const int tj = blockIdx.x, ti = blockIdx.y, b = blockIdx.z;
    const int i0 = ti * 64, j0 = tj * 64;
    const int t  = threadIdx.x;
    float* abase = attn + (size_t)b * TT * TT;
    if (tj > ti) {  // fully above diagonal: write zeros only
        for (int e = 0; e < 4; ++e) {
            int f = t + 256 * e;
            int row = f >> 4, c4 = (f & 15) * 4;
            *(float4*)(abase + (size_t)(i0 + row) * TT + j0 + c4) =
                make_float4(0.f, 0.f, 0.f, 0.f);
        }
        return;
    }
    __shared__ float qs[64 * 68];
    __shared__ float ks[64 * 68];
    for (int e = 0; e < 4; ++e) {
        int f = t + 256 * e;
        int row = f >> 4, h4 = (f & 15) * 4;
        *(float4*)(qs + row * 68 + h4) =
            *(const float4*)(qf + (size_t)(b * TT + i0 + row) * HD + h4);
        *(float4*)(ks + row * 68 + h4) =
            *(const float4*)(kf + (size_t)(b * TT + j0 + row) * HD + h4);
    }
    __syncthreads();
    const int tr = t >> 4, tc = t & 15;
    float acc[4][4] = {};
    for (int h4 = 0; h4 < 64; h4 += 4) {
        float4 qv[4], kv[4];
        for (int r = 0; r < 4; ++r)
            qv[r] = *(const float4*)(qs + (tr * 4 + r) * 68 + h4);
        for (int c = 0; c < 4; ++c)
            kv[c] = *(const float4*)(ks + (tc + 16 * c) * 68 + h4);
        for (int r = 0; r < 4; ++r)
            for (int c = 0; c < 4; ++c)
                acc[r][c] += qv[r].x * kv[c].x + qv[r].y * kv[c].y +
                             qv[r].z * kv[c].z + qv[r].w * kv[c].w;
    }
    float csum[4] = {0.f, 0.f, 0.f, 0.f};
    for (int r = 0; r < 4; ++r) {
        int gi = i0 + tr * 4 + r;
        for (int c = 0; c < 4; ++c) {
            int gj = j0 + tc + 16 * c;
            float e = (gj <= gi) ? __expf(acc[r][c] * SCALE) : 0.0f;
            abase[(size_t)gi * TT + gj] = e;
            csum[c] += e;
        }
    }
    __syncthreads();                 // done reading qs; reuse as reduction pad
    float* red = qs;                 // [16][64]
    for (int c = 0; c < 4; ++c) red[tr * 64 + tc + 16 * c] = csum[c];
    __syncthreads();
    if (t < 64) {
        float s = 0.f;
        for (int g = 0; g < 16; ++g) s += red[g * 64 + t];
        atomicAdd(&colsum[b * TT + j0 + t], s);
    }
}

// -------------------------------------------------------------- normpv ----
// Fused: attn[b][i][j] = E[b][i][j] * rcs[b][j]  (write back normalized)
//        out[b][i][h] += sum_j attn[b][i][j] * v[b][j][h]
__global__ __launch_bounds__(256) void normpv_kernel(
    const float* __restrict__ rcs, float* __restrict__ attn,
    const float* __restrict__ vf, float* __restrict__ out) {
    const int seg = blockIdx.x, ti = blockIdx.y, b = blockIdx.z;
    const int i0 = ti * 64;
    const int jstart = seg * 256;
    if (jstart > i0 + 63) return;
    const int jend = min(jstart + 256, i0 + 64);   // exclusive; 64-aligned
    __shared__ float as[64 * 68];
    __shared__ float vT[64 * 65];    // stride 65: transpose writes 2-way (free)
    const int t = threadIdx.x;
    const int tr = t >> 4, tc = t & 15;
    float* abase = attn + (size_t)b * TT * TT;
    float acc[4][4] = {};
    for (int jc = jstart; jc < jend; jc += 64) {
        __syncthreads();
        for (int e = 0; e < 4; ++e) {
            int f = t + 256 * e;
            int row = f >> 4, q4 = (f & 15) * 4;
            // E tile: normalize, write back to global, stash in LDS
            float* gp = abase + (size_t)(i0 + row) * TT + jc + q4;
            float4 a = *(const float4*)gp;
            const float4 rc = *(const float4*)(rcs + b * TT + jc + q4);
            a.x *= rc.x; a.y *= rc.y; a.z *= rc.z; a.w *= rc.w;
            *(float4*)gp = a;
            *(float4*)(as + row * 68 + q4) = a;
            // v tile transposed: vT[h][j-jc], stride 65
            float4 vv = *(const float4*)(vf + (size_t)(b * TT + jc + row) * HD + q4);
            vT[(q4 + 0) * 65 + row] = vv.x;
            vT[(q4 + 1) * 65 + row] = vv.y;
            vT[(q4 + 2) * 65 + row] = vv.z;
            vT[(q4 + 3) * 65 + row] = vv.w;
        }
        __syncthreads();
        for (int j4 = 0; j4 < 64; j4 += 4) {
            float4 av[4], vv[4];
            for (int r = 0; r < 4; ++r)
                av[r] = *(const float4*)(as + (tr * 4 + r) * 68 + j4);
            for (int c = 0; c < 4; ++c)
                vv[c] = *(const float4*)(vT + (tc + 16 * c) * 65 + j4);
            for (int r = 0; r < 4; ++r)
                for (int c = 0; c < 4; ++c)
                    acc[r][c] += av[r].x * vv[c].x + av[r].y * vv[c].y +
                                 av[r].z * vv[c].z + av[r].w * vv[c].w;
        }
    }
    for (int r = 0; r < 4; ++r)
        for (int c = 0; c < 4; ++c)
            atomicAdd(&out[(size_t)(b * TT + i0 + tr * 4 + r) * HD + tc + 16 * c],
                      acc[r][c]);
}

// -------------------------------------------------------------- launch ----
extern "C" void kernel_launch(void* const* d_in, const int* in_sizes, int n_in,
                              void* d_out, int out_size, void* d_ws, size_t ws_size,
                              hipStream_t stream) {
    const float* x  = (const float*)d_in[0];
    const float* Wk = (const float*)d_in[1];
    const float* Wq = (const float*)d_in[2];
    const float* Wv = (const float*)d_in[3];
    // d_in[4] = mask sentinel (causal always on) — unused.

    float* out  = (float*)d_out;                       // [B,T,64]
    float* attn = out + (size_t)NB * TT * HD;          // [B,T,T]

    // workspace: k,q,v fp32 [B*T*64] each + colsum [B*T]  (~12.6 MB)
    float* kf = (float*)d_ws;
    float* qf = kf + (size_t)NB * TT * HD;
    float* vf = qf + (size_t)NB * TT * HD;
    float* colsum = vf + (size_t)NB * TT * HD;

    hipLaunchKernelGGL(zero_kernel, dim3(16),   dim3(256), 0, stream, colsum, NB * TT);
    hipLaunchKernelGGL(zero_kernel, dim3(1024), dim3(256), 0, stream, out, NB * TT * HD);
    hipLaunchKernelGGL(qkv_kernel,  dim3(256, 3),     dim3(256), 0, stream,
                       x, Wk, Wq, Wv, kf, qf, vf);
    hipLaunchKernelGGL(scores_kernel, dim3(32, 32, 8), dim3(256), 0, stream,
                       qf, kf, attn, colsum);
    hipLaunchKernelGGL(rcp_kernel,  dim3(16),   dim3(256), 0, stream, colsum, NB * TT);
    hipLaunchKernelGGL(normpv_kernel, dim3(8, 32, 8),  dim3(256), 0, stream,
                       colsum, attn, vf, out);
}

// Round 4
// 248.240 us; speedup vs baseline: 1.4743x; 1.3892x over previous
//
#include <hip/hip_runtime.h>
#include <hip/hip_bf16.h>

// Problem constants (B=8, T=2048, d_model=512, head_dim=64)
#define TT 2048
#define NB 8
#define DM 512
#define HD 64
static constexpr float SCALE = 0.04419417382415922f; // 512^-0.5

typedef short  s16x8 __attribute__((ext_vector_type(8)));   // 8 bf16 (4 VGPRs)
typedef float  f32x4 __attribute__((ext_vector_type(4)));

#define MFMA(a, b, c) __builtin_amdgcn_mfma_f32_16x16x32_bf16((a), (b), (c), 0, 0, 0)

// fp32 -> bf16 (RNE)
static __device__ inline unsigned short f2bf(float f) {
    unsigned int u = __float_as_uint(f);
    u += 0x7FFFu + ((u >> 16) & 1u);
    return (unsigned short)(u >> 16);
}

// ---------------------------------------------------------------- zero ----
__global__ __launch_bounds__(256) void zero_kernel(float* __restrict__ p, int n) {
    int i = (blockIdx.x * 256 + threadIdx.x) * 4;
    if (i < n) *(float4*)(p + i) = make_float4(0.f, 0.f, 0.f, 0.f);
}

// ----------------------------------------------------------------- qkv ----
// Fused GEMM: out[row][0:192] = x[row][:] . {Wk,Wq,Wv}^T[:, 0:192], bf16 out.
// Block: 64 rows x 192 cols, K=512 in BK=64 steps. 4 waves, each 64x48.
#define QS 72   // LDS row stride in bf16 elements (64 + 8 pad)
__global__ __launch_bounds__(256) void qkv_kernel(
    const float* __restrict__ x, const float* __restrict__ Wk,
    const float* __restrict__ Wq, const float* __restrict__ Wv,
    unsigned short* __restrict__ kb, unsigned short* __restrict__ qb,
    unsigned short* __restrict__ vb) {
    __shared__ unsigned short xs[64 * QS];
    __shared__ unsigned short ws[192 * QS];
    const int i0 = blockIdx.x * 64;
    const int t = threadIdx.x;
    const int w = t >> 6, lane = t & 63;
    const int m15 = lane & 15, quad = lane >> 4;
    const int srow = t >> 2, cs = (t & 3) * 16;   // staging map
    f32x4 acc[4][3];
    for (int mt = 0; mt < 4; ++mt)
        for (int ct = 0; ct < 3; ++ct)
            acc[mt][ct] = (f32x4){0.f, 0.f, 0.f, 0.f};

    for (int kc = 0; kc < DM; kc += 64) {
        __syncthreads();
        // stage x tile (64x64 fp32 -> bf16)
        {
            const float* gp = x + (size_t)(i0 + srow) * DM + kc + cs;
            for (int half = 0; half < 2; ++half) {
                float4 f0 = *(const float4*)(gp + half * 8);
                float4 f1 = *(const float4*)(gp + half * 8 + 4);
                s16x8 h;
                h[0] = (short)f2bf(f0.x); h[1] = (short)f2bf(f0.y);
                h[2] = (short)f2bf(f0.z); h[3] = (short)f2bf(f0.w);
                h[4] = (short)f2bf(f1.x); h[5] = (short)f2bf(f1.y);
                h[6] = (short)f2bf(f1.z); h[7] = (short)f2bf(f1.w);
                *(s16x8*)(xs + srow * QS + cs + half * 8) = h;
            }
        }
        // stage W tiles (192x64 fp32 -> bf16); rep r -> {Wk,Wq,Wv}
        for (int rep = 0; rep < 3; ++rep) {
            const float* Wm = (rep == 0) ? Wk : (rep == 1) ? Wq : Wv;
            const float* gp = Wm + (size_t)srow * DM + kc + cs;
            for (int half = 0; half < 2; ++half) {
                float4 f0 = *(const float4*)(gp + half * 8);
                float4 f1 = *(const float4*)(gp + half * 8 + 4);
                s16x8 h;
                h[0] = (short)f2bf(f0.x); h[1] = (short)f2bf(f0.y);
                h[2] = (short)f2bf(f0.z); h[3] = (short)f2bf(f0.w);
                h[4] = (short)f2bf(f1.x); h[5] = (short)f2bf(f1.y);
                h[6] = (short)f2bf(f1.z); h[7] = (short)f2bf(f1.w);
                *(s16x8*)(ws + (rep * 64 + srow) * QS + cs + half * 8) = h;
            }
        }
        __syncthreads();
        for (int ks = 0; ks < 2; ++ks) {
            s16x8 a[4], b[3];
            for (int mt = 0; mt < 4; ++mt)
                a[mt] = *(const s16x8*)(xs + (mt * 16 + m15) * QS + ks * 32 + quad * 8);
            for (int ct = 0; ct < 3; ++ct)
                b[ct] = *(const s16x8*)(ws + ((w * 3 + ct) * 16 + m15) * QS + ks * 32 + quad * 8);
            for (int mt = 0; mt < 4; ++mt)
                for (int ct = 0; ct < 3; ++ct)
                    acc[mt][ct] = MFMA(a[mt], b[ct], acc[mt][ct]);
        }
    }
    // write bf16 outputs; tile16 = w*3+ct selects matrix + 16-col group
    for (int mt = 0; mt < 4; ++mt)
        for (int ct = 0; ct < 3; ++ct) {
            int tile16 = w * 3 + ct;
            unsigned short* outp = (tile16 < 4) ? kb : (tile16 < 8) ? qb : vb;
            int col = (tile16 & 3) * 16 + m15;
            for (int r = 0; r < 4; ++r) {
                int grow = i0 + mt * 16 + quad * 4 + r;
                outp[(size_t)grow * HD + col] = f2bf(acc[mt][ct][r]);
            }
        }
}

// -------------------------------------------------------------- colsum ----
// colsum[b][j] = sum_{i>=j} exp(SCALE * q_i . k_j)  — no E materialization.
// FIX (r3->r4): wave strips stride 16 within a 64-step loop -> all rows covered.
__global__ __launch_bounds__(256) void colsum_kernel(
    const unsigned short* __restrict__ qb, const unsigned short* __restrict__ kb,
    float* __restrict__ colsum) {
    const int jt = blockIdx.x, ich = blockIdx.y, b = blockIdx.z;
    const int j0 = jt * 64;
    const int iend = (ich + 1) * 512;
    if (iend <= j0) return;
    const int t = threadIdx.x;
    const int w = t >> 6, lane = t & 63;
    const int m15 = lane & 15, quad = lane >> 4;
    // K B-frags for this j-tile
    s16x8 bk[4][2];
    for (int ct = 0; ct < 4; ++ct)
        for (int ks = 0; ks < 2; ++ks)
            bk[ct][ks] = *(const s16x8*)(kb +
                (size_t)(b * TT + j0 + ct * 16 + m15) * HD + ks * 32 + quad * 8);
    float csum[4] = {0.f, 0.f, 0.f, 0.f};
    const int istart = max(ich * 512, j0);
    for (int it = istart + w * 16; it < iend; it += 64) {   // 4 waves x 16 rows = 64
        s16x8 aq[2];
        for (int ks = 0; ks < 2; ++ks)
            aq[ks] = *(const s16x8*)(qb +
                (size_t)(b * TT + it + m15) * HD + ks * 32 + quad * 8);
        for (int ct = 0; ct < 4; ++ct) {
            f32x4 s = (f32x4){0.f, 0.f, 0.f, 0.f};
            s = MFMA(aq[0], bk[ct][0], s);
            s = MFMA(aq[1], bk[ct][1], s);
            int gj = j0 + ct * 16 + m15;
            for (int r = 0; r < 4; ++r) {
                int gi = it + quad * 4 + r;
                float e = (gj <= gi) ? __expf(s[r] * SCALE) : 0.f;
                csum[ct] += e;
            }
        }
    }
    for (int ct = 0; ct < 4; ++ct) {
        csum[ct] += __shfl_xor(csum[ct], 16);
        csum[ct] += __shfl_xor(csum[ct], 32);
    }
    if (lane < 16)
        for (int ct = 0; ct < 4; ++ct)
            atomicAdd(&colsum[b * TT + j0 + ct * 16 + lane], csum[ct]);
}

// -------------------------------------------------------------- normpv ----
// Recompute S, normalize by colsum, write attn exactly once, PV via MFMA.
__global__ __launch_bounds__(256) void normpv_kernel(
    const unsigned short* __restrict__ qb, const unsigned short* __restrict__ kb,
    const unsigned short* __restrict__ vb, const float* __restrict__ colsum,
    float* __restrict__ attn, float* __restrict__ out) {
    const int jch = blockIdx.x;         // j range [jch*512, +512)
    const int ti = blockIdx.y, b = blockIdx.z;
    const int i0 = ti * 64;
    const int jbase = jch * 512;
    float* abase = attn + (size_t)b * TT * TT;
    const int t = threadIdx.x;
    if (jbase > i0 + 63) {              // fully above diagonal: zeros only
        const float4 z = make_float4(0.f, 0.f, 0.f, 0.f);
        for (int e = 0; e < 32; ++e) {
            int f4 = e * 256 + t;
            int row = f4 >> 7, c4 = (f4 & 127) * 4;
            *(float4*)(abase + (size_t)(i0 + row) * TT + jbase + c4) = z;
        }
        return;
    }
    const int w = t >> 6, lane = t & 63;
    const int m15 = lane & 15, quad = lane >> 4;
    __shared__ unsigned short vT[64 * QS];          // vT[h][j]
    __shared__ unsigned short ps[4 * 16 * QS];      // per-wave P strips
    unsigned short* psw = ps + w * 16 * QS;
    // Q A-frags for this wave's 16 rows (load once)
    s16x8 aq[2];
    for (int ks = 0; ks < 2; ++ks)
        aq[ks] = *(const s16x8*)(qb +
            (size_t)(b * TT + i0 + w * 16 + m15) * HD + ks * 32 + quad * 8);
    f32x4 o[4];
    for (int ht = 0; ht < 4; ++ht) o[ht] = (f32x4){0.f, 0.f, 0.f, 0.f};

    for (int jt = 0; jt < 8; ++jt) {
        const int j0 = jbase + jt * 64;
        __syncthreads();                 // protect vT/ps from prior-iter reads
        if (j0 > i0 + 63) {              // above-diagonal tile: zeros
            const float4 z = make_float4(0.f, 0.f, 0.f, 0.f);
            for (int e = 0; e < 4; ++e) {
                int f4 = e * 256 + t;
                int row = f4 >> 4, c4 = (f4 & 15) * 4;
                *(float4*)(abase + (size_t)(i0 + row) * TT + j0 + c4) = z;
            }
            continue;
        }
        // stage V tile transposed: vT[h][j]
        {
            int jr = t & 63, hs = (t >> 6) * 16;
            const unsigned short* vp = vb + (size_t)(b * TT + j0 + jr) * HD + hs;
            s16x8 v0 = *(const s16x8*)vp;
            s16x8 v1 = *(const s16x8*)(vp + 8);
            for (int q = 0; q < 8; ++q) vT[(hs + q) * QS + jr] = (unsigned short)v0[q];
            for (int q = 0; q < 8; ++q) vT[(hs + 8 + q) * QS + jr] = (unsigned short)v1[q];
        }
        // K B-frags
        s16x8 bk[4][2];
        for (int ct = 0; ct < 4; ++ct)
            for (int ks = 0; ks < 2; ++ks)
                bk[ct][ks] = *(const s16x8*)(kb +
                    (size_t)(b * TT + j0 + ct * 16 + m15) * HD + ks * 32 + quad * 8);
        // S = QK^T (same op order as colsum_kernel -> consistent E)
        for (int ct = 0; ct < 4; ++ct) {
            f32x4 s = (f32x4){0.f, 0.f, 0.f, 0.f};
            s = MFMA(aq[0], bk[ct][0], s);
            s = MFMA(aq[1], bk[ct][1], s);
            int gj = j0 + ct * 16 + m15;
            float rc = 1.0f / colsum[b * TT + gj];
            for (int r = 0; r < 4; ++r) {
                int gi = i0 + w * 16 + quad * 4 + r;
                float e = (gj <= gi) ? __expf(s[r] * SCALE) : 0.f;
                float a = e * rc;
                abase[(size_t)gi * TT + gj] = a;
                psw[(quad * 4 + r) * QS + ct * 16 + m15] = f2bf(a);
            }
        }
        __syncthreads();                 // vT/ps ready for all waves
        // O += P . V
        for (int ks = 0; ks < 2; ++ks) {
            s16x8 ap = *(const s16x8*)(psw + m15 * QS + ks * 32 + quad * 8);
            for (int ht = 0; ht < 4; ++ht) {
                s16x8 bv = *(const s16x8*)(vT + (ht * 16 + m15) * QS + ks * 32 + quad * 8);
                o[ht] = MFMA(ap, bv, o[ht]);
            }
        }
    }
    for (int ht = 0; ht < 4; ++ht)
        for (int r = 0; r < 4; ++r)
            atomicAdd(&out[(size_t)(b * TT + i0 + w * 16 + quad * 4 + r) * HD +
                           ht * 16 + m15], o[ht][r]);
}

// -------------------------------------------------------------- launch ----
extern "C" void kernel_launch(void* const* d_in, const int* in_sizes, int n_in,
                              void* d_out, int out_size, void* d_ws, size_t ws_size,
                              hipStream_t stream) {
    const float* x  = (const float*)d_in[0];
    const float* Wk = (const float*)d_in[1];
    const float* Wq = (const float*)d_in[2];
    const float* Wv = (const float*)d_in[3];
    // d_in[4] = mask sentinel (causal always on) — unused.

    float* out  = (float*)d_out;                       // [B,T,64]
    float* attn = out + (size_t)NB * TT * HD;          // [B,T,T]

    // workspace: k,q,v bf16 [B*T*64] each (2 MB ea) + colsum fp32 [B*T]
    unsigned short* kb = (unsigned short*)d_ws;
    unsigned short* qb = kb + (size_t)NB * TT * HD;
    unsigned short* vb = qb + (size_t)NB * TT * HD;
    float* colsum = (float*)(vb + (size_t)NB * TT * HD);

    hipLaunchKernelGGL(zero_kernel, dim3(16),   dim3(256), 0, stream,
                       colsum, NB * TT);
    hipLaunchKernelGGL(zero_kernel, dim3(1024), dim3(256), 0, stream,
                       out, NB * TT * HD);
    hipLaunchKernelGGL(qkv_kernel,  dim3(256),  dim3(256), 0, stream,
                       x, Wk, Wq, Wv, kb, qb, vb);
    hipLaunchKernelGGL(colsum_kernel, dim3(32, 4, 8), dim3(256), 0, stream,
                       qb, kb, colsum);
    hipLaunchKernelGGL(normpv_kernel, dim3(4, 32, 8), dim3(256), 0, stream,
                       qb, kb, vb, colsum, attn, out);
}

// Round 5
// 226.688 us; speedup vs baseline: 1.6144x; 1.0951x over previous
//
#include <hip/hip_runtime.h>
#include <hip/hip_bf16.h>

// Problem constants (B=8, T=2048, d_model=512, head_dim=64)
#define TT 2048
#define NB 8
#define DM 512
#define HD 64
static constexpr float SCALE = 0.04419417382415922f; // 512^-0.5

typedef short  s16x8 __attribute__((ext_vector_type(8)));   // 8 bf16 (4 VGPRs)
typedef float  f32x4 __attribute__((ext_vector_type(4)));

#define MFMA(a, b, c) __builtin_amdgcn_mfma_f32_16x16x32_bf16((a), (b), (c), 0, 0, 0)

// fp32 -> bf16 (RNE)
static __device__ inline unsigned short f2bf(float f) {
    unsigned int u = __float_as_uint(f);
    u += 0x7FFFu + ((u >> 16) & 1u);
    return (unsigned short)(u >> 16);
}

// ---------------------------------------------------------------- prep ----
// One launch: zero out (256 blk) + zero colsum (4 blk) + convert W->bf16 (96 blk)
__global__ __launch_bounds__(256) void prep_kernel(
    const float* __restrict__ Wk, const float* __restrict__ Wq,
    const float* __restrict__ Wv, unsigned short* __restrict__ wbf,
    float* __restrict__ colsum, float* __restrict__ out) {
    const int bi = blockIdx.x, t = threadIdx.x;
    if (bi < 256) {                      // zero out: 1,048,576 floats
        int i = (bi * 256 + t) * 4;
        *(float4*)(out + i) = make_float4(0.f, 0.f, 0.f, 0.f);
    } else if (bi < 260) {               // zero colsum: 16,384 floats
        int i = ((bi - 256) * 256 + t) * 4;
        *(float4*)(colsum + i) = make_float4(0.f, 0.f, 0.f, 0.f);
    } else {                             // convert W: 3*64*512 = 98,304 elems
        int g = ((bi - 260) * 256 + t) * 4;
        int mat = g >> 15, off = g & 32767;
        const float* src = (mat == 0) ? Wk : (mat == 1) ? Wq : Wv;
        float4 f = *(const float4*)(src + off);
        wbf[g + 0] = f2bf(f.x); wbf[g + 1] = f2bf(f.y);
        wbf[g + 2] = f2bf(f.z); wbf[g + 3] = f2bf(f.w);
    }
}

// ----------------------------------------------------------------- rcp ----
__global__ __launch_bounds__(256) void rcp_kernel(float* __restrict__ p) {
    int i = (blockIdx.x * 256 + threadIdx.x) * 4;
    float4 a = *(float4*)(p + i);
    a.x = 1.0f / a.x; a.y = 1.0f / a.y; a.z = 1.0f / a.z; a.w = 1.0f / a.w;
    *(float4*)(p + i) = a;
}

// ----------------------------------------------------------------- qkv ----
// M=32 rows/block, N=192 (all three matrices), K=512. Grid 512 blocks.
// x staged via LDS (fp32->bf16); W read directly from pre-converted bf16.
#define XS 72
__global__ __launch_bounds__(256) void qkv_kernel(
    const float* __restrict__ x, const unsigned short* __restrict__ wbf,
    unsigned short* __restrict__ kb, unsigned short* __restrict__ qb,
    unsigned short* __restrict__ vb) {
    __shared__ unsigned short xs[32 * XS];
    const int i0 = blockIdx.x * 32;
    const int t = threadIdx.x;
    const int w = t >> 6, lane = t & 63;
    const int m15 = lane & 15, quad = lane >> 4;
    const int srow = t >> 3, c8 = (t & 7) * 8;    // staging: 32 rows x 64 cols
    f32x4 acc[2][3];
    for (int mt = 0; mt < 2; ++mt)
        for (int ct = 0; ct < 3; ++ct)
            acc[mt][ct] = (f32x4){0.f, 0.f, 0.f, 0.f};

    for (int kc = 0; kc < DM; kc += 64) {
        __syncthreads();
        {
            const float* gp = x + (size_t)(i0 + srow) * DM + kc + c8;
            float4 f0 = *(const float4*)gp;
            float4 f1 = *(const float4*)(gp + 4);
            s16x8 h;
            h[0] = (short)f2bf(f0.x); h[1] = (short)f2bf(f0.y);
            h[2] = (short)f2bf(f0.z); h[3] = (short)f2bf(f0.w);
            h[4] = (short)f2bf(f1.x); h[5] = (short)f2bf(f1.y);
            h[6] = (short)f2bf(f1.z); h[7] = (short)f2bf(f1.w);
            *(s16x8*)(xs + srow * XS + c8) = h;
        }
        __syncthreads();
        for (int ks = 0; ks < 2; ++ks) {
            s16x8 a[2];
            for (int mt = 0; mt < 2; ++mt)
                a[mt] = *(const s16x8*)(xs + (mt * 16 + m15) * XS + ks * 32 + quad * 8);
            for (int ct = 0; ct < 3; ++ct) {
                s16x8 bfr = *(const s16x8*)(wbf +
                    (size_t)((w * 3 + ct) * 16 + m15) * DM + kc + ks * 32 + quad * 8);
                acc[0][ct] = MFMA(a[0], bfr, acc[0][ct]);
                acc[1][ct] = MFMA(a[1], bfr, acc[1][ct]);
            }
        }
    }
    for (int mt = 0; mt < 2; ++mt)
        for (int ct = 0; ct < 3; ++ct) {
            int tile16 = w * 3 + ct;
            unsigned short* outp = (tile16 < 4) ? kb : (tile16 < 8) ? qb : vb;
            int col = (tile16 & 3) * 16 + m15;
            for (int r = 0; r < 4; ++r) {
                int grow = i0 + mt * 16 + quad * 4 + r;
                outp[(size_t)grow * HD + col] = f2bf(acc[mt][ct][r]);
            }
        }
}

// -------------------------------------------------------------- colsum ----
// colsum[b][j] = sum_{i>=j} exp(SCALE * q_i . k_j)  — no E materialization.
__global__ __launch_bounds__(256) void colsum_kernel(
    const unsigned short* __restrict__ qb, const unsigned short* __restrict__ kb,
    float* __restrict__ colsum) {
    const int jt = blockIdx.x, ich = blockIdx.y, b = blockIdx.z;
    const int j0 = jt * 64;
    const int iend = (ich + 1) * 512;
    if (iend <= j0) return;
    const int t = threadIdx.x;
    const int w = t >> 6, lane = t & 63;
    const int m15 = lane & 15, quad = lane >> 4;
    s16x8 bk[4][2];
    for (int ct = 0; ct < 4; ++ct)
        for (int ks = 0; ks < 2; ++ks)
            bk[ct][ks] = *(const s16x8*)(kb +
                (size_t)(b * TT + j0 + ct * 16 + m15) * HD + ks * 32 + quad * 8);
    float csum[4] = {0.f, 0.f, 0.f, 0.f};
    const int istart = max(ich * 512, j0);
    for (int it = istart + w * 16; it < iend; it += 64) {   // 4 waves x 16 rows
        s16x8 aq[2];
        for (int ks = 0; ks < 2; ++ks)
            aq[ks] = *(const s16x8*)(qb +
                (size_t)(b * TT + it + m15) * HD + ks * 32 + quad * 8);
        for (int ct = 0; ct < 4; ++ct) {
            f32x4 s = (f32x4){0.f, 0.f, 0.f, 0.f};
            s = MFMA(aq[0], bk[ct][0], s);
            s = MFMA(aq[1], bk[ct][1], s);
            int gj = j0 + ct * 16 + m15;
            for (int r = 0; r < 4; ++r) {
                int gi = it + quad * 4 + r;
                float e = (gj <= gi) ? __expf(s[r] * SCALE) : 0.f;
                csum[ct] += e;
            }
        }
    }
    for (int ct = 0; ct < 4; ++ct) {
        csum[ct] += __shfl_xor(csum[ct], 16);
        csum[ct] += __shfl_xor(csum[ct], 32);
    }
    if (lane < 16)
        for (int ct = 0; ct < 4; ++ct)
            atomicAdd(&colsum[b * TT + j0 + ct * 16 + lane], csum[ct]);
}

// -------------------------------------------------------------- normpv ----
// Recompute S, scale by rcs (reciprocal colsum), write attn once, PV via MFMA.
// jch covers 512 j-cols; V staged per 256-col half; ps is wave-private
// (no barrier needed: DS ops are in-order within a wave).
#define VS 264
#define PS 72
__global__ __launch_bounds__(256) void normpv_kernel(
    const unsigned short* __restrict__ qb, const unsigned short* __restrict__ kb,
    const unsigned short* __restrict__ vb, const float* __restrict__ rcs,
    float* __restrict__ attn, float* __restrict__ out) {
    const int jch = blockIdx.x;          // j range [jch*512, +512)
    const int ti = blockIdx.y, b = blockIdx.z;
    const int i0 = ti * 64;
    const int jbase = jch * 512;
    float* abase = attn + (size_t)b * TT * TT;
    const int t = threadIdx.x;
    const float4 z = make_float4(0.f, 0.f, 0.f, 0.f);
    if (jbase > i0 + 63) {               // fully above diagonal: zeros only
        for (int e = 0; e < 32; ++e) {
            int f4 = e * 256 + t;
            int row = f4 >> 7, c4 = (f4 & 127) * 4;
            *(float4*)(abase + (size_t)(i0 + row) * TT + jbase + c4) = z;
        }
        return;
    }
    const int w = t >> 6, lane = t & 63;
    const int m15 = lane & 15, quad = lane >> 4;
    __shared__ unsigned short vT[64 * VS];      // vT[h][j-jh], 256-col chunk
    __shared__ unsigned short ps[4 * 16 * PS];  // per-wave P strips (private)
    unsigned short* psw = ps + w * 16 * PS;
    s16x8 aq[2];
    for (int ks = 0; ks < 2; ++ks)
        aq[ks] = *(const s16x8*)(qb +
            (size_t)(b * TT + i0 + w * 16 + m15) * HD + ks * 32 + quad * 8);
    f32x4 o[4];
    for (int ht = 0; ht < 4; ++ht) o[ht] = (f32x4){0.f, 0.f, 0.f, 0.f};
    const float* rcb = rcs + b * TT;

    for (int half = 0; half < 2; ++half) {
        const int jh = jbase + half * 256;
        if (jh > i0 + 63) {              // zero 64x256 region (block-uniform)
            for (int e = 0; e < 16; ++e) {
                int f4 = e * 256 + t;
                int row = f4 >> 6, c4 = (f4 & 63) * 4;
                *(float4*)(abase + (size_t)(i0 + row) * TT + jh + c4) = z;
            }
            continue;
        }
        __syncthreads();                 // all waves done reading prior vT
        {   // stage vT: thread t owns v row (jh + t)
            const unsigned short* vp = vb + (size_t)(b * TT + jh + t) * HD;
            for (int seg = 0; seg < 8; ++seg) {
                s16x8 vv = *(const s16x8*)(vp + seg * 8);
                for (int q = 0; q < 8; ++q)
                    vT[(seg * 8 + q) * VS + t] = (unsigned short)vv[q];
            }
        }
        __syncthreads();                 // vT ready
        for (int jt2 = 0; jt2 < 4; ++jt2) {
            const int j0 = jh + jt2 * 64;
            if (j0 > i0 + 63) {          // zero 64x64 tile (block-uniform)
                for (int e = 0; e < 4; ++e) {
                    int f4 = e * 256 + t;
                    int row = f4 >> 4, c4 = (f4 & 15) * 4;
                    *(float4*)(abase + (size_t)(i0 + row) * TT + j0 + c4) = z;
                }
                continue;
            }
            s16x8 bk[4][2];
            for (int ct = 0; ct < 4; ++ct)
                for (int ks = 0; ks < 2; ++ks)
                    bk[ct][ks] = *(const s16x8*)(kb +
                        (size_t)(b * TT + j0 + ct * 16 + m15) * HD + ks * 32 + quad * 8);
            for (int ct = 0; ct < 4; ++ct) {
                f32x4 s = (f32x4){0.f, 0.f, 0.f, 0.f};
                s = MFMA(aq[0], bk[ct][0], s);
                s = MFMA(aq[1], bk[ct][1], s);
                int gj = j0 + ct * 16 + m15;
                float rc = rcb[gj];
                for (int r = 0; r < 4; ++r) {
                    int gi = i0 + w * 16 + quad * 4 + r;
                    float e = (gj <= gi) ? __expf(s[r] * SCALE) : 0.f;
                    float a = e * rc;
                    abase[(size_t)gi * TT + gj] = a;
                    psw[(quad * 4 + r) * PS + ct * 16 + m15] = f2bf(a);
                }
            }
            // PV: psw is wave-private; DS in-order per wave -> no barrier
            for (int ks = 0; ks < 2; ++ks) {
                s16x8 ap = *(const s16x8*)(psw + m15 * PS + ks * 32 + quad * 8);
                for (int ht = 0; ht < 4; ++ht) {
                    s16x8 bv = *(const s16x8*)(vT +
                        (ht * 16 + m15) * VS + jt2 * 64 + ks * 32 + quad * 8);
                    o[ht] = MFMA(ap, bv, o[ht]);
                }
            }
        }
    }
    for (int ht = 0; ht < 4; ++ht)
        for (int r = 0; r < 4; ++r)
            atomicAdd(&out[(size_t)(b * TT + i0 + w * 16 + quad * 4 + r) * HD +
                           ht * 16 + m15], o[ht][r]);
}

// -------------------------------------------------------------- launch ----
extern "C" void kernel_launch(void* const* d_in, const int* in_sizes, int n_in,
                              void* d_out, int out_size, void* d_ws, size_t ws_size,
                              hipStream_t stream) {
    const float* x  = (const float*)d_in[0];
    const float* Wk = (const float*)d_in[1];
    const float* Wq = (const float*)d_in[2];
    const float* Wv = (const float*)d_in[3];
    // d_in[4] = mask sentinel (causal always on) — unused.

    float* out  = (float*)d_out;                       // [B,T,64]
    float* attn = out + (size_t)NB * TT * HD;          // [B,T,T]

    // workspace: k,q,v bf16 (2 MB ea) + colsum fp32 (64 KB) + wbf bf16 (196 KB)
    unsigned short* kb = (unsigned short*)d_ws;
    unsigned short* qb = kb + (size_t)NB * TT * HD;
    unsigned short* vb = qb + (size_t)NB * TT * HD;
    float* colsum = (float*)(vb + (size_t)NB * TT * HD);
    unsigned short* wbf = (unsigned short*)(colsum + NB * TT);

    hipLaunchKernelGGL(prep_kernel, dim3(356), dim3(256), 0, stream,
                       Wk, Wq, Wv, wbf, colsum, out);
    hipLaunchKernelGGL(qkv_kernel,  dim3(512), dim3(256), 0, stream,
                       x, wbf, kb, qb, vb);
    hipLaunchKernelGGL(colsum_kernel, dim3(32, 4, 8), dim3(256), 0, stream,
                       qb, kb, colsum);
    hipLaunchKernelGGL(rcp_kernel,  dim3(16), dim3(256), 0, stream, colsum);
    hipLaunchKernelGGL(normpv_kernel, dim3(4, 32, 8), dim3(256), 0, stream,
                       qb, kb, vb, colsum, attn, out);
}